// Round 10
// baseline (705.229 us; speedup 1.0000x reference)
//
#include <hip/hip_runtime.h>
#include <hip/hip_bf16.h>

#define NN 100000
#define EE 3200000
#define GG 128
#define D_IN 128
#define D_H 256
#define D_OUT 64
#define BN_EPS 1e-3f
#define PAD 96        // max in-degree slots (Poisson(32): P(deg>=96) < 1e-19)
#define LDSTRIDE 40   // 32 + 8 pad ushorts
#define AST 136       // fused layer-0 A-tile stride (128 + 8 pad ushorts)
#define X8SCALE 16.0f
#define X8INV   0.0625f

// bucketed CSR build
#define NBUCK 782         // ceil(100000 / 128)
#define BUCKET_CAP 5120   // mean 4096, sigma 64 -> 16 sigma headroom
#define EPT 8             // edges per thread in k_bucket (391 WGs -> all 256 CUs busy)

// GEMM grid: 782 row tiles (BM=128) x 2 col tiles (BN=128), XCD-chunk swizzled
// 1564 = 8*195 + 4
#define GEMM_NWG 1564

typedef __hip_bfloat16 bf16;
typedef __attribute__((ext_vector_type(8))) short short8;
typedef __attribute__((ext_vector_type(4))) float float4v;
typedef __attribute__((ext_vector_type(2))) float float2v;
typedef __attribute__((ext_vector_type(4))) int intv4;
typedef __attribute__((ext_vector_type(4))) unsigned short usv4;

#if __has_builtin(__builtin_amdgcn_cvt_pk_f32_fp8) && __has_builtin(__builtin_amdgcn_cvt_pk_fp8_f32)
#define HAVE_FP8_CVT 1
#endif

// ---------------- fp16 bit helpers (state/weights are fp16: 11-bit mantissa > bf16's 8) ----
__device__ inline float h2f(unsigned short s) {
    _Float16 h; __builtin_memcpy(&h, &s, 2); return (float)h;
}
__device__ inline unsigned short f2h(float f) {
    _Float16 h = (_Float16)f; unsigned short s; __builtin_memcpy(&s, &h, 2); return s;
}
__device__ inline float4 load4h(const unsigned short* p) {
    ushort4 u = *(const ushort4*)p;
    return make_float4(h2f(u.x), h2f(u.y), h2f(u.z), h2f(u.w));
}
__device__ inline void store4h(unsigned short* p, float4 v) {
    ushort4 u;
    u.x = f2h(v.x); u.y = f2h(v.y); u.z = f2h(v.z); u.w = f2h(v.w);
    *(ushort4*)p = u;
}
__device__ inline float4 load4h_nt(const unsigned short* p) {
    usv4 u = __builtin_nontemporal_load((const usv4*)p);
    return make_float4(h2f(u.x), h2f(u.y), h2f(u.z), h2f(u.w));
}

// ---------------- fp8 e4m3 helpers ----------------
__device__ inline unsigned char enc_fp8(float f) {
#ifdef HAVE_FP8_CVT
    int r = __builtin_amdgcn_cvt_pk_fp8_f32(f, f, 0, false);
    return (unsigned char)(r & 0xFF);
#else
    union { float f; unsigned u; } c; c.f = f;
    unsigned s = (c.u >> 31) << 7;
    float a = fabsf(f);
    if (!(a >= 0.015625f)) {
        int q = (int)rintf(a * 512.0f);
        return (unsigned char)(s | (unsigned)q);
    }
    if (a >= 464.0f) return (unsigned char)(s | 0x7E);
    int e = (int)((c.u >> 23) & 0xFF) - 127;
    int q = (int)rintf(ldexpf(a, 3 - e));
    if (q == 16) { q = 8; e += 1; }
    return (unsigned char)(s | ((unsigned)(e + 7) << 3) | (unsigned)(q - 8));
#endif
}
__device__ inline unsigned int enc4_fp8(float4 v) {
#ifdef HAVE_FP8_CVT
    int r = __builtin_amdgcn_cvt_pk_fp8_f32(v.x, v.y, 0, false);
    r = __builtin_amdgcn_cvt_pk_fp8_f32(v.z, v.w, r, true);
    return (unsigned int)r;
#else
    return (unsigned int)enc_fp8(v.x) | ((unsigned int)enc_fp8(v.y) << 8)
         | ((unsigned int)enc_fp8(v.z) << 16) | ((unsigned int)enc_fp8(v.w) << 24);
#endif
}
__device__ inline float4 dec4_fp8(unsigned int w) {
#ifdef HAVE_FP8_CVT
    float2v lo = __builtin_amdgcn_cvt_pk_f32_fp8((int)w, false);
    float2v hi = __builtin_amdgcn_cvt_pk_f32_fp8((int)w, true);
    return make_float4(lo.x, lo.y, hi.x, hi.y);
#else
    float4 o;
    unsigned b0 = w & 0xFF, b1 = (w >> 8) & 0xFF, b2 = (w >> 16) & 0xFF, b3 = w >> 24;
    auto d1 = [](unsigned b) -> float {
        unsigned s = b >> 7, e = (b >> 3) & 0xF, m = b & 7;
        float v = e ? ldexpf((float)(8 + m), (int)e - 10) : ldexpf((float)m, -9);
        return s ? -v : v;
    };
    o.x = d1(b0); o.y = d1(b1); o.z = d1(b2); o.w = d1(b3);
    return o;
#endif
}

// bijective XCD-chunk swizzle: 1564 = 8*195 + 4; XCD x gets a contiguous chunk
__device__ inline int xcd_swz_gemm(int bid) {
    int x = bid & 7, i = bid >> 3;
    return (x < 4 ? x * 196 : 784 + (x - 4) * 195) + i;
}

// ---------------- phase 1: dual bucket scatter, ONE histogram pass ----------------
__global__ __launch_bounds__(1024) void k_bucket(const int* __restrict__ src,
                                                 const int* __restrict__ dst,
                                                 int* __restrict__ cursor,
                                                 int* __restrict__ scursor,
                                                 int* __restrict__ ebuf,
                                                 unsigned char* __restrict__ sbuf, int e) {
    __shared__ int hist[NBUCK];
    __shared__ int base[NBUCK];
    __shared__ int shist[NBUCK];
    __shared__ int sbase[NBUCK];
    int t = threadIdx.x;
    for (int i = t; i < NBUCK; i += 1024) { hist[i] = 0; shist[i] = 0; }
    __syncthreads();
    int e0 = blockIdx.x * (1024 * EPT) + t;
    int vals[EPT]; int bks[EPT]; int pk[EPT];
#pragma unroll
    for (int j = 0; j < EPT; ++j) {
        int idx = e0 + j * 1024;
        bks[j] = -1;
        if (idx < e) {
            int s = src[idx], d = dst[idx];
            bks[j] = d >> 7;
            vals[j] = (s << 7) | (d & 127);
            int r1 = atomicAdd(&hist[d >> 7], 1);
            int r2 = atomicAdd(&shist[s >> 7], 1);
            pk[j] = r1 | (r2 << 16);       // per-(WG,bucket) counts << 2^16
        }
    }
    __syncthreads();
    for (int i = t; i < NBUCK; i += 1024) {
        int c = hist[i];
        base[i] = c ? atomicAdd(&cursor[i], c) : 0;
        int sc = shist[i];
        sbase[i] = sc ? atomicAdd(&scursor[i], sc) : 0;
    }
    __syncthreads();
#pragma unroll
    for (int j = 0; j < EPT; ++j) {
        if (bks[j] >= 0) {
            int v = vals[j];
            int rel = base[bks[j]] + (pk[j] & 0xFFFF);
            if (rel < BUCKET_CAP) ebuf[bks[j] * BUCKET_CAP + rel] = v;
            int sbk = v >> 14;             // == src >> 7
            int srel = sbase[sbk] + (pk[j] >> 16);
            if (srel < BUCKET_CAP) sbuf[(size_t)sbk * BUCKET_CAP + srel] = (unsigned char)((v >> 7) & 127);
        }
    }
}

// ---------------- phase 2: per-bucket padded-CSR fill + norms + fp8 h-convert fused ----------
__global__ __launch_bounds__(512) void k_fill(const int* __restrict__ cursor,
                                              const int* __restrict__ scursor,
                                              const int* __restrict__ ebuf,
                                              const unsigned char* __restrict__ sbuf,
                                              const float* __restrict__ h,
                                              int* __restrict__ col_pad,
                                              int* __restrict__ deg_in,
                                              float* __restrict__ norm_src,
                                              float* __restrict__ norm_dst,
                                              unsigned int* __restrict__ xh8) {
    __shared__ int lcol[128 * PAD];        // 49152 B
    __shared__ int ldeg[128];
    __shared__ int lodeg[128];
    int b = blockIdx.x;
    int t = threadIdx.x;
    if (t < 128) { ldeg[t] = 0; lodeg[t] = 0; }
    __syncthreads();
    int cnt = cursor[b]; if (cnt > BUCKET_CAP) cnt = BUCKET_CAP;
    const int* eb = ebuf + b * BUCKET_CAP;
    for (int i = t; i < cnt; i += 512) {
        int v = eb[i];
        int node = v & 127;
        int s = v >> 7;
        int pos = atomicAdd(&ldeg[node], 1);
        if (pos < PAD) lcol[node * PAD + pos] = s;
    }
    int scnt = scursor[b]; if (scnt > BUCKET_CAP) scnt = BUCKET_CAP;
    const unsigned char* sb = sbuf + (size_t)b * BUCKET_CAP;
    for (int i = t; i < scnt; i += 512) {
        atomicAdd(&lodeg[sb[i]], 1);
    }
    __syncthreads();
    int n0 = b << 7;
    int nn = NN - n0; if (nn > 128) nn = 128;
    int q = (nn * PAD) >> 2;               // PAD=96 -> divisible by 4
    int4* gdst = (int4*)(col_pad + (size_t)n0 * PAD);
    const int4* lsrc = (const int4*)lcol;
    for (int i = t; i < q; i += 512) gdst[i] = lsrc[i];   // garbage beyond deg: never read
    if (t < nn) {
        int node = n0 + t;
        int din = ldeg[t];
        int dout = lodeg[t];
        deg_in[node] = din;
        norm_dst[node] = rsqrtf((float)(din < 1 ? 1 : din));
        norm_src[node] = rsqrtf((float)(dout < 1 ? 1 : dout));
    }
    // fused convert: xh8[row] = fp8(h[row] * norm_src[row] * 16) for this bucket's rows
    for (int i = t; i < nn * 32; i += 512) {
        int row = i >> 5, w = i & 31;
        int dout = lodeg[row];
        float s = rsqrtf((float)(dout < 1 ? 1 : dout)) * X8SCALE;
        float4 v = *(const float4*)(h + (size_t)(n0 + row) * D_IN + w * 4);
        v.x *= s; v.y *= s; v.z *= s; v.w *= s;
        xh8[(size_t)(n0 + row) * 32 + w] = enc4_fp8(v);
    }
}

// ---------------- W: fp32 [K][256] -> transposed fp16 [256][K] (single, no hi/lo) ----------
__global__ __launch_bounds__(256) void k_splitw(const float* __restrict__ W0,
                                                const float* __restrict__ Wl,
                                                unsigned short* __restrict__ wsplit) {
    int b = blockIdx.x;            // 0..639
    int n = threadIdx.x;           // 0..255
    const float* Wsrc; unsigned short* T; int K, k;
    if (b < 128)      { k = b;       K = 128; Wsrc = W0;          T = wsplit; }
    else if (b < 384) { k = b - 128; K = 256; Wsrc = Wl;          T = wsplit + 32768; }
    else              { k = b - 384; K = 256; Wsrc = Wl + 65536;  T = wsplit + 98304; }
    T[n * K + k] = f2h(Wsrc[k * 256 + n]);
}

// ---- fused layer 0: fp8 gather (spmm0) -> LDS fp16 A-tile -> MFMA GEMM + bias/BN/ReLU -> H ----
// 512 threads (8 waves). Gather: 8 passes x 16 rows (wave handles 2 rows, 32-lane halves).
// GEMM: BM=128 x BN=256, A staged ONCE in LDS for all 4 K-steps; B = W0^T streamed (L2-hot).
__global__ __launch_bounds__(512) void k_l0fused(const unsigned char* __restrict__ x8,
                                                 const int* __restrict__ deg_in,
                                                 const int* __restrict__ col_pad,
                                                 const float* __restrict__ norm_dst,
                                                 const unsigned short* __restrict__ WT,
                                                 const float* __restrict__ bias,
                                                 const float* __restrict__ gamma,
                                                 const float* __restrict__ beta,
                                                 const float* __restrict__ mean,
                                                 const float* __restrict__ var,
                                                 unsigned short* __restrict__ H, int M) {
    __shared__ __align__(16) unsigned short As[128 * AST];   // 34816 B
    __shared__ __align__(16) unsigned short Bf[256 * LDSTRIDE]; // 20480 B
    int tid = threadIdx.x;
    int wv = tid >> 6;          // 0..7
    int lane = tid & 63;
    int half = lane >> 5;
    int dl = lane & 31;
    unsigned lb = (unsigned)dl << 2;
    int bm0 = blockIdx.x * 128;

    // ---- gather phase ----
    for (int p = 0; p < 8; ++p) {
        int lr = p * 16 + wv * 2 + half;
        int r = bm0 + lr;
        if (r < M) {
            int d = deg_in[r]; if (d > PAD) d = PAD;
            int e0 = r * PAD, e1 = e0 + d;
            float ax = 0.f, ay = 0.f, az = 0.f, aw = 0.f;
            int e = e0;
            for (; e + 15 < e1; e += 16) {
                const intv4* cp = (const intv4*)(col_pad + e);
                intv4 i0 = __builtin_nontemporal_load(cp);
                intv4 i1 = __builtin_nontemporal_load(cp + 1);
                intv4 i2 = __builtin_nontemporal_load(cp + 2);
                intv4 i3 = __builtin_nontemporal_load(cp + 3);
                int s[16] = {i0.x, i0.y, i0.z, i0.w, i1.x, i1.y, i1.z, i1.w,
                             i2.x, i2.y, i2.z, i2.w, i3.x, i3.y, i3.z, i3.w};
                unsigned int w[16];
#pragma unroll
                for (int j = 0; j < 16; ++j)
                    w[j] = *(const unsigned int*)(x8 + ((((unsigned)s[j]) << 7) | lb));
#pragma unroll
                for (int j = 0; j < 16; ++j) {
                    float4 v = dec4_fp8(w[j]);
                    ax += v.x; ay += v.y; az += v.z; aw += v.w;
                }
            }
            for (; e + 7 < e1; e += 8) {
                const intv4* cp = (const intv4*)(col_pad + e);
                intv4 i0 = __builtin_nontemporal_load(cp);
                intv4 i1 = __builtin_nontemporal_load(cp + 1);
                int s[8] = {i0.x, i0.y, i0.z, i0.w, i1.x, i1.y, i1.z, i1.w};
                unsigned int w[8];
#pragma unroll
                for (int j = 0; j < 8; ++j)
                    w[j] = *(const unsigned int*)(x8 + ((((unsigned)s[j]) << 7) | lb));
#pragma unroll
                for (int j = 0; j < 8; ++j) {
                    float4 v = dec4_fp8(w[j]);
                    ax += v.x; ay += v.y; az += v.z; aw += v.w;
                }
            }
            for (; e < e1; ++e) {
                float4 v = dec4_fp8(*(const unsigned int*)(x8 + ((((unsigned)col_pad[e]) << 7) | lb)));
                ax += v.x; ay += v.y; az += v.z; aw += v.w;
            }
            float nd = norm_dst[r] * X8INV;
            ushort4 u;
            u.x = f2h(ax * nd); u.y = f2h(ay * nd); u.z = f2h(az * nd); u.w = f2h(aw * nd);
            *(ushort4*)&As[lr * AST + dl * 4] = u;
        }
    }
    __syncthreads();

    // ---- GEMM phase: 128x256, K=128, 4 K-steps ----
    int quad = lane >> 4, l15 = lane & 15;
    int srow = tid >> 1, sseg = tid & 1;   // 256 B-rows, 2 segs of 16 ushorts
    float4v acc[16];
#pragma unroll
    for (int j = 0; j < 16; ++j) acc[j] = (float4v){0.f, 0.f, 0.f, 0.f};

    for (int k0 = 0; k0 < 128; k0 += 32) {
        const ushort4* wr = (const ushort4*)(WT + (size_t)srow * 128 + k0 + sseg * 16);
        ushort4 b0 = wr[0], b1 = wr[1], b2 = wr[2], b3 = wr[3];
        ushort4* bd = (ushort4*)&Bf[srow * LDSTRIDE + sseg * 16];
        bd[0] = b0; bd[1] = b1; bd[2] = b2; bd[3] = b3;
        __syncthreads();
        short8 a = *(const short8*)&As[(wv * 16 + l15) * AST + k0 + quad * 8];
#pragma unroll
        for (int nt = 0; nt < 16; ++nt) {
            short8 bfr = *(const short8*)&Bf[(nt * 16 + l15) * LDSTRIDE + quad * 8];
            acc[nt] = __builtin_amdgcn_mfma_f32_16x16x32_f16(a, bfr, acc[nt], 0, 0, 0);
        }
        __syncthreads();
    }
#pragma unroll
    for (int nt = 0; nt < 16; ++nt) {
        int col = nt * 16 + l15;
        float sc = rsqrtf(var[col] + BN_EPS) * gamma[col];
        float off = (bias[col] - mean[col]) * sc + beta[col];
#pragma unroll
        for (int reg = 0; reg < 4; ++reg) {
            int m = bm0 + wv * 16 + quad * 4 + reg;
            if (m < M) {
                float o = fmaxf(acc[nt][reg] * sc + off, 0.f);
                H[(size_t)m * D_H + col] = f2h(o);
            }
        }
    }
}

// ---- layers 1,2 fp16 GEMM 128x128: epilogue = rowscale (norm_src) * X8SCALE, store fp8 X ----
__global__ __launch_bounds__(256) void k_gemm_x(const unsigned short* __restrict__ A,
                                                const unsigned short* __restrict__ WT,
                                                const float* __restrict__ rowscale,
                                                unsigned char* __restrict__ X8,
                                                int M, int K) {
    __shared__ __align__(16) unsigned short lds[2 * 128 * LDSTRIDE];
    unsigned short* As = lds;
    unsigned short* Bf = lds + 128 * LDSTRIDE;
    int tid = threadIdx.x, wave = tid >> 6, lane = tid & 63, quad = lane >> 4, l15 = lane & 15;
    int sw = xcd_swz_gemm(blockIdx.x);
    int bm0 = (sw >> 1) * 128, bn0 = (sw & 1) * 128;
    int srow = tid >> 1, sseg = tid & 1;   // 128 rows, 2 segs of 16 cols
    int agrow = bm0 + srow;
    float4v acc[2][8];
#pragma unroll
    for (int i = 0; i < 2; ++i)
#pragma unroll
        for (int j = 0; j < 8; ++j) acc[i][j] = (float4v){0.f, 0.f, 0.f, 0.f};

    for (int k0 = 0; k0 < K; k0 += 32) {
        ushort4 a0 = make_ushort4(0, 0, 0, 0), a1 = a0, a2 = a0, a3 = a0;
        if (agrow < M) {
            const ushort4* ap = (const ushort4*)(A + (size_t)agrow * K + k0 + sseg * 16);
            a0 = ap[0]; a1 = ap[1]; a2 = ap[2]; a3 = ap[3];
        }
        ushort4* ad = (ushort4*)&As[srow * LDSTRIDE + sseg * 16];
        ad[0] = a0; ad[1] = a1; ad[2] = a2; ad[3] = a3;
        const ushort4* wh = (const ushort4*)(WT + (size_t)(bn0 + srow) * K + k0 + sseg * 16);
        ushort4* bd = (ushort4*)&Bf[srow * LDSTRIDE + sseg * 16];
        bd[0] = wh[0]; bd[1] = wh[1]; bd[2] = wh[2]; bd[3] = wh[3];
        __syncthreads();
        short8 a0f = *(const short8*)&As[(wave * 32 + l15) * LDSTRIDE + quad * 8];
        short8 a1f = *(const short8*)&As[(wave * 32 + 16 + l15) * LDSTRIDE + quad * 8];
#pragma unroll
        for (int nt = 0; nt < 8; ++nt) {
            short8 bf = *(const short8*)&Bf[(nt * 16 + l15) * LDSTRIDE + quad * 8];
            acc[0][nt] = __builtin_amdgcn_mfma_f32_16x16x32_f16(a0f, bf, acc[0][nt], 0, 0, 0);
            acc[1][nt] = __builtin_amdgcn_mfma_f32_16x16x32_f16(a1f, bf, acc[1][nt], 0, 0, 0);
        }
        __syncthreads();
    }
#pragma unroll
    for (int rt = 0; rt < 2; ++rt) {
#pragma unroll
        for (int reg = 0; reg < 4; ++reg) {
            int m = bm0 + wave * 32 + rt * 16 + quad * 4 + reg;
            if (m < M) {
                float s = rowscale[m] * X8SCALE;
#pragma unroll
                for (int nt = 0; nt < 8; ++nt) {
                    int col = bn0 + nt * 16 + l15;
                    X8[(size_t)m * D_H + col] = enc_fp8(acc[rt][nt][reg] * s);
                }
            }
        }
    }
}

// ---- spmm layers 1,2: fp8 gather (lane-per-dword, MLP=16), BN+ReLU+residual; fp16 state ----
__global__ __launch_bounds__(256) void k_spmm12(const unsigned char* __restrict__ x8,
                                                const int* __restrict__ deg_in,
                                                const int* __restrict__ col_pad,
                                                const float* __restrict__ norm_dst,
                                                const float* __restrict__ bias,
                                                const float* __restrict__ gamma,
                                                const float* __restrict__ beta,
                                                const float* __restrict__ mean,
                                                const float* __restrict__ var,
                                                unsigned short* __restrict__ H, int n) {
    int wv = __builtin_amdgcn_readfirstlane(threadIdx.x >> 6);
    int r = blockIdx.x * 4 + wv;
    if (r >= n) return;
    int lane = threadIdx.x & 63;
    unsigned lb = (unsigned)lane << 2;      // byte offset of lane's dword in a 256B row
    int c = lane * 4;                       // dim base
    int d = deg_in[r]; if (d > PAD) d = PAD;
    int e0 = r * PAD, e1 = e0 + d;
    float ax = 0.f, ay = 0.f, az = 0.f, aw = 0.f;
    int e = e0;
    for (; e + 15 < e1; e += 16) {
        const intv4* cp = (const intv4*)(col_pad + e);
        intv4 i0 = __builtin_nontemporal_load(cp);
        intv4 i1 = __builtin_nontemporal_load(cp + 1);
        intv4 i2 = __builtin_nontemporal_load(cp + 2);
        intv4 i3 = __builtin_nontemporal_load(cp + 3);
        int s[16] = {i0.x, i0.y, i0.z, i0.w, i1.x, i1.y, i1.z, i1.w,
                     i2.x, i2.y, i2.z, i2.w, i3.x, i3.y, i3.z, i3.w};
        unsigned int w[16];
#pragma unroll
        for (int j = 0; j < 16; ++j)
            w[j] = *(const unsigned int*)(x8 + ((((unsigned)s[j]) << 8) | lb));
#pragma unroll
        for (int j = 0; j < 16; ++j) {
            float4 v = dec4_fp8(w[j]);
            ax += v.x; ay += v.y; az += v.z; aw += v.w;
        }
    }
    for (; e + 7 < e1; e += 8) {
        const intv4* cp = (const intv4*)(col_pad + e);
        intv4 i0 = __builtin_nontemporal_load(cp);
        intv4 i1 = __builtin_nontemporal_load(cp + 1);
        int s[8] = {i0.x, i0.y, i0.z, i0.w, i1.x, i1.y, i1.z, i1.w};
        unsigned int w[8];
#pragma unroll
        for (int j = 0; j < 8; ++j)
            w[j] = *(const unsigned int*)(x8 + ((((unsigned)s[j]) << 8) | lb));
#pragma unroll
        for (int j = 0; j < 8; ++j) {
            float4 v = dec4_fp8(w[j]);
            ax += v.x; ay += v.y; az += v.z; aw += v.w;
        }
    }
    for (; e < e1; ++e) {
        float4 v = dec4_fp8(*(const unsigned int*)(x8 + ((((unsigned)col_pad[e]) << 8) | lb)));
        ax += v.x; ay += v.y; az += v.z; aw += v.w;
    }
    float nd = norm_dst[r] * X8INV;
    float4 b4  = *(const float4*)(bias + c);
    float4 g4  = *(const float4*)(gamma + c);
    float4 be4 = *(const float4*)(beta + c);
    float4 m4  = *(const float4*)(mean + c);
    float4 v4  = *(const float4*)(var + c);
    float4 rv = load4h_nt(H + (size_t)r * D_H + c);   // residual read (line overwritten below)
    float4 o;
    o.x = fmaxf((ax * nd + b4.x - m4.x) * rsqrtf(v4.x + BN_EPS) * g4.x + be4.x, 0.f) + rv.x;
    o.y = fmaxf((ay * nd + b4.y - m4.y) * rsqrtf(v4.y + BN_EPS) * g4.y + be4.y, 0.f) + rv.y;
    o.z = fmaxf((az * nd + b4.z - m4.z) * rsqrtf(v4.z + BN_EPS) * g4.z + be4.z, 0.f) + rv.z;
    o.w = fmaxf((aw * nd + b4.w - m4.w) * rsqrtf(v4.w + BN_EPS) * g4.w + be4.w, 0.f) + rv.w;
    store4h(H + (size_t)r * D_H + c, o);
}

// ---------------- segmented mean-pool (graph_ids sorted), fp16 input ----------------
__global__ __launch_bounds__(256) void k_pool(const unsigned short* __restrict__ h,
                                              const int* __restrict__ gid,
                                              float* __restrict__ pooled,
                                              float* __restrict__ counts, int n) {
    int wave = threadIdx.x >> 6;
    int lane = threadIdx.x & 63;
    int base = blockIdx.x * 256 + wave * 64;
    if (base >= n) return;
    int c = lane * 4;
    int end = base + 64; if (end > n) end = n;
    float ax = 0.f, ay = 0.f, az = 0.f, aw = 0.f;
    int cnt = 0, cur = -1;
    for (int i = base; i < end; ++i) {
        int g = gid[i];
        if (g != cur) {
            if (cnt > 0) {
                atomicAdd(&pooled[cur * D_H + c + 0], ax);
                atomicAdd(&pooled[cur * D_H + c + 1], ay);
                atomicAdd(&pooled[cur * D_H + c + 2], az);
                atomicAdd(&pooled[cur * D_H + c + 3], aw);
                if (lane == 0) atomicAdd(&counts[cur], (float)cnt);
            }
            cur = g; cnt = 0; ax = ay = az = aw = 0.f;
        }
        float4 v = load4h(h + (size_t)i * D_H + c);
        ax += v.x; ay += v.y; az += v.z; aw += v.w;
        cnt++;
    }
    if (cnt > 0) {
        atomicAdd(&pooled[cur * D_H + c + 0], ax);
        atomicAdd(&pooled[cur * D_H + c + 1], ay);
        atomicAdd(&pooled[cur * D_H + c + 2], az);
        atomicAdd(&pooled[cur * D_H + c + 3], aw);
        if (lane == 0) atomicAdd(&counts[cur], (float)cnt);
    }
}

// -------- head: out[g] = (pooled[g]/count[g]) @ Wp + bp  (fp32 in/out) --------
__global__ __launch_bounds__(64) void k_head(const float* __restrict__ pooled,
                                             const float* __restrict__ counts,
                                             const float* __restrict__ Wp,
                                             const float* __restrict__ bp,
                                             float* __restrict__ out) {
    int g = blockIdx.x;
    int t = threadIdx.x;
    __shared__ float p[D_H];
    float inv = 1.0f / fmaxf(counts[g], 1.0f);
    for (int k = t; k < D_H; k += 64) p[k] = pooled[g * D_H + k] * inv;
    __syncthreads();
    float acc = bp[t];
#pragma unroll 8
    for (int k = 0; k < D_H; ++k) acc = fmaf(p[k], Wp[k * D_OUT + t], acc);
    out[g * D_OUT + t] = acc;
}

extern "C" void kernel_launch(void* const* d_in, const int* in_sizes, int n_in,
                              void* d_out, int out_size, void* d_ws, size_t ws_size,
                              hipStream_t stream) {
    (void)in_sizes; (void)n_in; (void)out_size; (void)ws_size;
    const float* h        = (const float*)d_in[0];
    const float* W0       = (const float*)d_in[1];
    const float* b0       = (const float*)d_in[2];
    const float* Wl       = (const float*)d_in[3];
    const float* bl       = (const float*)d_in[4];
    const float* bn_gamma = (const float*)d_in[5];
    const float* bn_beta  = (const float*)d_in[6];
    const float* bn_mean  = (const float*)d_in[7];
    const float* bn_var   = (const float*)d_in[8];
    const float* Wp       = (const float*)d_in[9];
    const float* bp       = (const float*)d_in[10];
    const int*   src      = (const int*)d_in[11];
    const int*   dst      = (const int*)d_in[12];
    const int*   gid      = (const int*)d_in[13];
    float* out = (float*)d_out;

    char* ws = (char*)d_ws;
    size_t off = 0;
    auto alloc = [&](size_t bytes) -> void* {
        void* p = ws + off;
        off += (bytes + 255) & ~(size_t)255;
        return p;
    };
    unsigned int*   bufXh8 = (unsigned int*)alloc((size_t)NN * D_IN);       // fp8 h*ns (12.8 MB)
    unsigned char*  bufX8  = (unsigned char*)alloc((size_t)NN * D_H);       // fp8 messages (25.6 MB)
    unsigned short* bufH   = (unsigned short*)alloc((size_t)NN * D_H * 2);  // fp16 state (51.2 MB)
    int*   col_pad  = (int*)alloc(((size_t)NN * PAD + 64) * 4);             // 38.4 MB
    float* norm_src = (float*)alloc((size_t)NN * 4);
    float* norm_dst = (float*)alloc((size_t)NN * 4);
    int*   degs     = (int*)alloc(((size_t)NN + 2 * NBUCK) * 4);
    int*   deg_in   = degs;
    int*   cursor   = degs + NN;                                            // NBUCK ints
    int*   scursor  = degs + NN + NBUCK;                                    // NBUCK ints
    unsigned short* wsplit = (unsigned short*)alloc(163840 * 2);            // fp16 W transposed
    float* pooled   = (float*)alloc((size_t)(GG * D_H + GG) * 4);
    float* counts   = pooled + GG * D_H;

    // bucketed edge buffer aliases bufX8 (dead until layer-1 k_gemm_x): 16.0 MB <= 25.6 MB
    int* ebuf = (int*)bufX8;
    // src-bucket byte buffer aliases bufH (dead until k_l0fused writes H): 4.0 MB <= 51.2 MB
    unsigned char* sbuf = (unsigned char*)bufH;

    unsigned short* w0T = wsplit;            // [256][128]
    unsigned short* w1T = wsplit + 32768;    // [256][256]
    unsigned short* w2T = wsplit + 98304;    // [256][256]

    hipMemsetAsync(cursor, 0, (size_t)2 * NBUCK * 4, stream);
    hipMemsetAsync(pooled, 0, (size_t)(GG * D_H + GG) * 4, stream);

    const int NB = (NN + 255) / 256;
    const int SB = (NN + 3) / 4;

    k_splitw<<<640, 256, 0, stream>>>(W0, Wl, wsplit);
    k_bucket<<<(EE + 1024 * EPT - 1) / (1024 * EPT), 1024, 0, stream>>>(
        src, dst, cursor, scursor, ebuf, sbuf, EE);
    k_fill<<<NBUCK, 512, 0, stream>>>(cursor, scursor, ebuf, sbuf, h, col_pad, deg_in,
                                      norm_src, norm_dst, bufXh8);

    // layer 0: fused gather + GEMM + BN + ReLU
    k_l0fused<<<NBUCK, 512, 0, stream>>>((const unsigned char*)bufXh8, deg_in, col_pad,
                                         norm_dst, w0T, b0,
                                         bn_gamma, bn_beta, bn_mean, bn_var, bufH, NN);
    // layer 1 (fp8 messages)
    k_gemm_x<<<GEMM_NWG, 256, 0, stream>>>(bufH, w1T, norm_src, bufX8, NN, D_H);
    k_spmm12<<<SB, 256, 0, stream>>>(bufX8, deg_in, col_pad, norm_dst, bl,
                                     bn_gamma + D_H, bn_beta + D_H,
                                     bn_mean + D_H, bn_var + D_H, bufH, NN);
    // layer 2
    k_gemm_x<<<GEMM_NWG, 256, 0, stream>>>(bufH, w2T, norm_src, bufX8, NN, D_H);
    k_spmm12<<<SB, 256, 0, stream>>>(bufX8, deg_in, col_pad, norm_dst, bl + D_H,
                                     bn_gamma + 2 * D_H, bn_beta + 2 * D_H,
                                     bn_mean + 2 * D_H, bn_var + 2 * D_H, bufH, NN);

    k_pool<<<NB, 256, 0, stream>>>(bufH, gid, pooled, counts, NN);
    k_head<<<GG, 64, 0, stream>>>(pooled, counts, Wp, bp, out);
}

// Round 11
// 670.951 us; speedup vs baseline: 1.0511x; 1.0511x over previous
//
#include <hip/hip_runtime.h>
#include <hip/hip_bf16.h>

#define NN 100000
#define EE 3200000
#define GG 128
#define D_IN 128
#define D_H 256
#define D_OUT 64
#define BN_EPS 1e-3f
#define PAD 96        // max in-degree slots (Poisson(32): P(deg>=96) < 1e-19)
#define LDSTRIDE 40   // 32 + 8 pad ushorts
#define X8SCALE 16.0f
#define X8INV   0.0625f

// bucketed CSR build
#define NBUCK 782         // ceil(100000 / 128)
#define BUCKET_CAP 5120   // mean 4096, sigma 64 -> 16 sigma headroom
#define EPT 8             // edges per thread in k_bucket (391 WGs -> all 256 CUs busy)

// GEMM grid: 782 row tiles (BM=128) x 2 col tiles (BN=128), XCD-chunk swizzled
// 1564 = 8*195 + 4
#define GEMM_NWG 1564

typedef __hip_bfloat16 bf16;
typedef __attribute__((ext_vector_type(8))) short short8;
typedef __attribute__((ext_vector_type(4))) float float4v;
typedef __attribute__((ext_vector_type(2))) float float2v;
typedef __attribute__((ext_vector_type(4))) int intv4;
typedef __attribute__((ext_vector_type(4))) unsigned short usv4;

#if __has_builtin(__builtin_amdgcn_cvt_pk_f32_fp8) && __has_builtin(__builtin_amdgcn_cvt_pk_fp8_f32)
#define HAVE_FP8_CVT 1
#endif

// ---------------- fp16 bit helpers (state/weights are fp16: 11-bit mantissa > bf16's 8) ----
__device__ inline float h2f(unsigned short s) {
    _Float16 h; __builtin_memcpy(&h, &s, 2); return (float)h;
}
__device__ inline unsigned short f2h(float f) {
    _Float16 h = (_Float16)f; unsigned short s; __builtin_memcpy(&s, &h, 2); return s;
}
__device__ inline float4 load4h(const unsigned short* p) {
    ushort4 u = *(const ushort4*)p;
    return make_float4(h2f(u.x), h2f(u.y), h2f(u.z), h2f(u.w));
}
__device__ inline void store4h(unsigned short* p, float4 v) {
    ushort4 u;
    u.x = f2h(v.x); u.y = f2h(v.y); u.z = f2h(v.z); u.w = f2h(v.w);
    *(ushort4*)p = u;
}
__device__ inline float4 load4h_nt(const unsigned short* p) {
    usv4 u = __builtin_nontemporal_load((const usv4*)p);
    return make_float4(h2f(u.x), h2f(u.y), h2f(u.z), h2f(u.w));
}

// ---------------- fp8 e4m3 helpers ----------------
__device__ inline unsigned char enc_fp8(float f) {
#ifdef HAVE_FP8_CVT
    int r = __builtin_amdgcn_cvt_pk_fp8_f32(f, f, 0, false);
    return (unsigned char)(r & 0xFF);
#else
    union { float f; unsigned u; } c; c.f = f;
    unsigned s = (c.u >> 31) << 7;
    float a = fabsf(f);
    if (!(a >= 0.015625f)) {
        int q = (int)rintf(a * 512.0f);
        return (unsigned char)(s | (unsigned)q);
    }
    if (a >= 464.0f) return (unsigned char)(s | 0x7E);
    int e = (int)((c.u >> 23) & 0xFF) - 127;
    int q = (int)rintf(ldexpf(a, 3 - e));
    if (q == 16) { q = 8; e += 1; }
    return (unsigned char)(s | ((unsigned)(e + 7) << 3) | (unsigned)(q - 8));
#endif
}
__device__ inline unsigned int enc4_fp8(float4 v) {
#ifdef HAVE_FP8_CVT
    int r = __builtin_amdgcn_cvt_pk_fp8_f32(v.x, v.y, 0, false);
    r = __builtin_amdgcn_cvt_pk_fp8_f32(v.z, v.w, r, true);
    return (unsigned int)r;
#else
    return (unsigned int)enc_fp8(v.x) | ((unsigned int)enc_fp8(v.y) << 8)
         | ((unsigned int)enc_fp8(v.z) << 16) | ((unsigned int)enc_fp8(v.w) << 24);
#endif
}
__device__ inline float4 dec4_fp8(unsigned int w) {
#ifdef HAVE_FP8_CVT
    float2v lo = __builtin_amdgcn_cvt_pk_f32_fp8((int)w, false);
    float2v hi = __builtin_amdgcn_cvt_pk_f32_fp8((int)w, true);
    return make_float4(lo.x, lo.y, hi.x, hi.y);
#else
    float4 o;
    unsigned b0 = w & 0xFF, b1 = (w >> 8) & 0xFF, b2 = (w >> 16) & 0xFF, b3 = w >> 24;
    auto d1 = [](unsigned b) -> float {
        unsigned s = b >> 7, e = (b >> 3) & 0xF, m = b & 7;
        float v = e ? ldexpf((float)(8 + m), (int)e - 10) : ldexpf((float)m, -9);
        return s ? -v : v;
    };
    o.x = d1(b0); o.y = d1(b1); o.z = d1(b2); o.w = d1(b3);
    return o;
#endif
}

// bijective XCD-chunk swizzle: 1564 = 8*195 + 4; XCD x gets a contiguous chunk
__device__ inline int xcd_swz_gemm(int bid) {
    int x = bid & 7, i = bid >> 3;
    return (x < 4 ? x * 196 : 784 + (x - 4) * 195) + i;
}

// ---------------- phase 1: dual bucket scatter, ONE histogram pass ----------------
__global__ __launch_bounds__(1024) void k_bucket(const int* __restrict__ src,
                                                 const int* __restrict__ dst,
                                                 int* __restrict__ cursor,
                                                 int* __restrict__ scursor,
                                                 int* __restrict__ ebuf,
                                                 unsigned char* __restrict__ sbuf, int e) {
    __shared__ int hist[NBUCK];
    __shared__ int base[NBUCK];
    __shared__ int shist[NBUCK];
    __shared__ int sbase[NBUCK];
    int t = threadIdx.x;
    for (int i = t; i < NBUCK; i += 1024) { hist[i] = 0; shist[i] = 0; }
    __syncthreads();
    int e0 = blockIdx.x * (1024 * EPT) + t;
    int vals[EPT]; int bks[EPT]; int pk[EPT];
#pragma unroll
    for (int j = 0; j < EPT; ++j) {
        int idx = e0 + j * 1024;
        bks[j] = -1;
        if (idx < e) {
            int s = src[idx], d = dst[idx];
            bks[j] = d >> 7;
            vals[j] = (s << 7) | (d & 127);
            int r1 = atomicAdd(&hist[d >> 7], 1);
            int r2 = atomicAdd(&shist[s >> 7], 1);
            pk[j] = r1 | (r2 << 16);       // per-(WG,bucket) counts << 2^16
        }
    }
    __syncthreads();
    for (int i = t; i < NBUCK; i += 1024) {
        int c = hist[i];
        base[i] = c ? atomicAdd(&cursor[i], c) : 0;
        int sc = shist[i];
        sbase[i] = sc ? atomicAdd(&scursor[i], sc) : 0;
    }
    __syncthreads();
#pragma unroll
    for (int j = 0; j < EPT; ++j) {
        if (bks[j] >= 0) {
            int v = vals[j];
            int rel = base[bks[j]] + (pk[j] & 0xFFFF);
            if (rel < BUCKET_CAP) ebuf[bks[j] * BUCKET_CAP + rel] = v;
            int sbk = v >> 14;             // == src >> 7
            int srel = sbase[sbk] + (pk[j] >> 16);
            if (srel < BUCKET_CAP) sbuf[(size_t)sbk * BUCKET_CAP + srel] = (unsigned char)((v >> 7) & 127);
        }
    }
}

// ---------------- phase 2: per-bucket padded-CSR fill + norms + fp8 h-convert fused ----------
__global__ __launch_bounds__(512) void k_fill(const int* __restrict__ cursor,
                                              const int* __restrict__ scursor,
                                              const int* __restrict__ ebuf,
                                              const unsigned char* __restrict__ sbuf,
                                              const float* __restrict__ h,
                                              int* __restrict__ col_pad,
                                              int* __restrict__ deg_in,
                                              float* __restrict__ norm_src,
                                              float* __restrict__ norm_dst,
                                              unsigned int* __restrict__ xh8) {
    __shared__ int lcol[128 * PAD];        // 49152 B
    __shared__ int ldeg[128];
    __shared__ int lodeg[128];
    int b = blockIdx.x;
    int t = threadIdx.x;
    if (t < 128) { ldeg[t] = 0; lodeg[t] = 0; }
    __syncthreads();
    int cnt = cursor[b]; if (cnt > BUCKET_CAP) cnt = BUCKET_CAP;
    const int* eb = ebuf + b * BUCKET_CAP;
    for (int i = t; i < cnt; i += 512) {
        int v = eb[i];
        int node = v & 127;
        int s = v >> 7;
        int pos = atomicAdd(&ldeg[node], 1);
        if (pos < PAD) lcol[node * PAD + pos] = s;
    }
    int scnt = scursor[b]; if (scnt > BUCKET_CAP) scnt = BUCKET_CAP;
    const unsigned char* sb = sbuf + (size_t)b * BUCKET_CAP;
    for (int i = t; i < scnt; i += 512) {
        atomicAdd(&lodeg[sb[i]], 1);
    }
    __syncthreads();
    int n0 = b << 7;
    int nn = NN - n0; if (nn > 128) nn = 128;
    int q = (nn * PAD) >> 2;               // PAD=96 -> divisible by 4
    int4* gdst = (int4*)(col_pad + (size_t)n0 * PAD);
    const int4* lsrc = (const int4*)lcol;
    for (int i = t; i < q; i += 512) gdst[i] = lsrc[i];   // garbage beyond deg: never read
    if (t < nn) {
        int node = n0 + t;
        int din = ldeg[t];
        int dout = lodeg[t];
        deg_in[node] = din;
        norm_dst[node] = rsqrtf((float)(din < 1 ? 1 : din));
        norm_src[node] = rsqrtf((float)(dout < 1 ? 1 : dout));
    }
    // fused convert: xh8[row] = fp8(h[row] * norm_src[row] * 16) for this bucket's rows
    for (int i = t; i < nn * 32; i += 512) {
        int row = i >> 5, w = i & 31;
        int dout = lodeg[row];
        float s = rsqrtf((float)(dout < 1 ? 1 : dout)) * X8SCALE;
        float4 v = *(const float4*)(h + (size_t)(n0 + row) * D_IN + w * 4);
        v.x *= s; v.y *= s; v.z *= s; v.w *= s;
        xh8[(size_t)(n0 + row) * 32 + w] = enc4_fp8(v);
    }
}

// ---------------- W: fp32 [K][256] -> transposed fp16 [256][K] (single, no hi/lo) ----------
__global__ __launch_bounds__(256) void k_splitw(const float* __restrict__ W0,
                                                const float* __restrict__ Wl,
                                                unsigned short* __restrict__ wsplit) {
    int b = blockIdx.x;            // 0..639
    int n = threadIdx.x;           // 0..255
    const float* Wsrc; unsigned short* T; int K, k;
    if (b < 128)      { k = b;       K = 128; Wsrc = W0;          T = wsplit; }
    else if (b < 384) { k = b - 128; K = 256; Wsrc = Wl;          T = wsplit + 32768; }
    else              { k = b - 384; K = 256; Wsrc = Wl + 65536;  T = wsplit + 98304; }
    T[n * K + k] = f2h(Wsrc[k * 256 + n]);
}

// --- spmm0: p[r] = norm_dst[r]/16 * sum xh8[s]; fp8 gather, 2 rows/wave, MLP=16 ---
__global__ __launch_bounds__(256) void k_spmm0(const unsigned char* __restrict__ x8,
                                               const int* __restrict__ deg_in,
                                               const int* __restrict__ col_pad,
                                               const float* __restrict__ norm_dst,
                                               unsigned short* __restrict__ p, int n) {
    int wv   = threadIdx.x >> 6;
    int lane = threadIdx.x & 63;
    int half = lane >> 5;
    int dl   = lane & 31;          // dword slot (4 dims) within 32-word row
    unsigned lb = (unsigned)dl << 2;
    int r = blockIdx.x * 8 + wv * 2 + half;
    if (r >= n) return;
    int d = deg_in[r]; if (d > PAD) d = PAD;
    int e0 = r * PAD, e1 = e0 + d;
    float ax = 0.f, ay = 0.f, az = 0.f, aw = 0.f;
    int e = e0;
    for (; e + 15 < e1; e += 16) {
        const intv4* cp = (const intv4*)(col_pad + e);
        intv4 i0 = __builtin_nontemporal_load(cp);
        intv4 i1 = __builtin_nontemporal_load(cp + 1);
        intv4 i2 = __builtin_nontemporal_load(cp + 2);
        intv4 i3 = __builtin_nontemporal_load(cp + 3);
        int s[16] = {i0.x, i0.y, i0.z, i0.w, i1.x, i1.y, i1.z, i1.w,
                     i2.x, i2.y, i2.z, i2.w, i3.x, i3.y, i3.z, i3.w};
        unsigned int w[16];
#pragma unroll
        for (int j = 0; j < 16; ++j)
            w[j] = *(const unsigned int*)(x8 + ((((unsigned)s[j]) << 7) | lb));
#pragma unroll
        for (int j = 0; j < 16; ++j) {
            float4 v = dec4_fp8(w[j]);
            ax += v.x; ay += v.y; az += v.z; aw += v.w;
        }
    }
    for (; e + 7 < e1; e += 8) {
        const intv4* cp = (const intv4*)(col_pad + e);
        intv4 i0 = __builtin_nontemporal_load(cp);
        intv4 i1 = __builtin_nontemporal_load(cp + 1);
        int s[8] = {i0.x, i0.y, i0.z, i0.w, i1.x, i1.y, i1.z, i1.w};
        unsigned int w[8];
#pragma unroll
        for (int j = 0; j < 8; ++j)
            w[j] = *(const unsigned int*)(x8 + ((((unsigned)s[j]) << 7) | lb));
#pragma unroll
        for (int j = 0; j < 8; ++j) {
            float4 v = dec4_fp8(w[j]);
            ax += v.x; ay += v.y; az += v.z; aw += v.w;
        }
    }
    for (; e < e1; ++e) {
        float4 v = dec4_fp8(*(const unsigned int*)(x8 + ((((unsigned)col_pad[e]) << 7) | lb)));
        ax += v.x; ay += v.y; az += v.z; aw += v.w;
    }
    float nd = norm_dst[r] * X8INV;
    store4h(p + (size_t)r * D_IN + dl * 4,
            make_float4(ax * nd, ay * nd, az * nd, aw * nd));
}

// ---------------- MFMA fp16 GEMM 128x128, layer-0: epilogue = +bias, BN, ReLU -> H fp16 ----
__global__ __launch_bounds__(256) void k_gemm_bn(const unsigned short* __restrict__ A,
                                                 const unsigned short* __restrict__ WT,
                                                 const float* __restrict__ bias,
                                                 const float* __restrict__ gamma,
                                                 const float* __restrict__ beta,
                                                 const float* __restrict__ mean,
                                                 const float* __restrict__ var,
                                                 unsigned short* __restrict__ H,
                                                 int M, int K) {
    __shared__ __align__(16) unsigned short lds[2 * 128 * LDSTRIDE];
    unsigned short* As = lds;
    unsigned short* Bf = lds + 128 * LDSTRIDE;
    int tid = threadIdx.x, wave = tid >> 6, lane = tid & 63, quad = lane >> 4, l15 = lane & 15;
    int sw = xcd_swz_gemm(blockIdx.x);
    int bm0 = (sw >> 1) * 128, bn0 = (sw & 1) * 128;
    int srow = tid >> 1, sseg = tid & 1;   // 128 rows, 2 segs of 16 cols
    int agrow = bm0 + srow;
    float4v acc[2][8];
#pragma unroll
    for (int i = 0; i < 2; ++i)
#pragma unroll
        for (int j = 0; j < 8; ++j) acc[i][j] = (float4v){0.f, 0.f, 0.f, 0.f};

    for (int k0 = 0; k0 < K; k0 += 32) {
        ushort4 a0 = make_ushort4(0, 0, 0, 0), a1 = a0, a2 = a0, a3 = a0;
        if (agrow < M) {
            const ushort4* ap = (const ushort4*)(A + (size_t)agrow * K + k0 + sseg * 16);
            a0 = ap[0]; a1 = ap[1]; a2 = ap[2]; a3 = ap[3];
        }
        ushort4* ad = (ushort4*)&As[srow * LDSTRIDE + sseg * 16];
        ad[0] = a0; ad[1] = a1; ad[2] = a2; ad[3] = a3;
        const ushort4* wh = (const ushort4*)(WT + (size_t)(bn0 + srow) * K + k0 + sseg * 16);
        ushort4* bd = (ushort4*)&Bf[srow * LDSTRIDE + sseg * 16];
        bd[0] = wh[0]; bd[1] = wh[1]; bd[2] = wh[2]; bd[3] = wh[3];
        __syncthreads();
        short8 a0f = *(const short8*)&As[(wave * 32 + l15) * LDSTRIDE + quad * 8];
        short8 a1f = *(const short8*)&As[(wave * 32 + 16 + l15) * LDSTRIDE + quad * 8];
#pragma unroll
        for (int nt = 0; nt < 8; ++nt) {
            short8 bf = *(const short8*)&Bf[(nt * 16 + l15) * LDSTRIDE + quad * 8];
            acc[0][nt] = __builtin_amdgcn_mfma_f32_16x16x32_f16(a0f, bf, acc[0][nt], 0, 0, 0);
            acc[1][nt] = __builtin_amdgcn_mfma_f32_16x16x32_f16(a1f, bf, acc[1][nt], 0, 0, 0);
        }
        __syncthreads();
    }
#pragma unroll
    for (int nt = 0; nt < 8; ++nt) {
        int col = bn0 + nt * 16 + l15;
        float sc = rsqrtf(var[col] + BN_EPS) * gamma[col];
        float off = (bias[col] - mean[col]) * sc + beta[col];
#pragma unroll
        for (int rt = 0; rt < 2; ++rt) {
#pragma unroll
            for (int reg = 0; reg < 4; ++reg) {
                int m = bm0 + wave * 32 + rt * 16 + quad * 4 + reg;
                if (m < M) {
                    float o = fmaxf(acc[rt][nt][reg] * sc + off, 0.f);
                    H[(size_t)m * D_H + col] = f2h(o);
                }
            }
        }
    }
}

// ---- layers 1,2 fp16 GEMM 128x128: epilogue = rowscale (norm_src) * X8SCALE, store fp8 X ----
__global__ __launch_bounds__(256) void k_gemm_x(const unsigned short* __restrict__ A,
                                                const unsigned short* __restrict__ WT,
                                                const float* __restrict__ rowscale,
                                                unsigned char* __restrict__ X8,
                                                int M, int K) {
    __shared__ __align__(16) unsigned short lds[2 * 128 * LDSTRIDE];
    unsigned short* As = lds;
    unsigned short* Bf = lds + 128 * LDSTRIDE;
    int tid = threadIdx.x, wave = tid >> 6, lane = tid & 63, quad = lane >> 4, l15 = lane & 15;
    int sw = xcd_swz_gemm(blockIdx.x);
    int bm0 = (sw >> 1) * 128, bn0 = (sw & 1) * 128;
    int srow = tid >> 1, sseg = tid & 1;   // 128 rows, 2 segs of 16 cols
    int agrow = bm0 + srow;
    float4v acc[2][8];
#pragma unroll
    for (int i = 0; i < 2; ++i)
#pragma unroll
        for (int j = 0; j < 8; ++j) acc[i][j] = (float4v){0.f, 0.f, 0.f, 0.f};

    for (int k0 = 0; k0 < K; k0 += 32) {
        ushort4 a0 = make_ushort4(0, 0, 0, 0), a1 = a0, a2 = a0, a3 = a0;
        if (agrow < M) {
            const ushort4* ap = (const ushort4*)(A + (size_t)agrow * K + k0 + sseg * 16);
            a0 = ap[0]; a1 = ap[1]; a2 = ap[2]; a3 = ap[3];
        }
        ushort4* ad = (ushort4*)&As[srow * LDSTRIDE + sseg * 16];
        ad[0] = a0; ad[1] = a1; ad[2] = a2; ad[3] = a3;
        const ushort4* wh = (const ushort4*)(WT + (size_t)(bn0 + srow) * K + k0 + sseg * 16);
        ushort4* bd = (ushort4*)&Bf[srow * LDSTRIDE + sseg * 16];
        bd[0] = wh[0]; bd[1] = wh[1]; bd[2] = wh[2]; bd[3] = wh[3];
        __syncthreads();
        short8 a0f = *(const short8*)&As[(wave * 32 + l15) * LDSTRIDE + quad * 8];
        short8 a1f = *(const short8*)&As[(wave * 32 + 16 + l15) * LDSTRIDE + quad * 8];
#pragma unroll
        for (int nt = 0; nt < 8; ++nt) {
            short8 bf = *(const short8*)&Bf[(nt * 16 + l15) * LDSTRIDE + quad * 8];
            acc[0][nt] = __builtin_amdgcn_mfma_f32_16x16x32_f16(a0f, bf, acc[0][nt], 0, 0, 0);
            acc[1][nt] = __builtin_amdgcn_mfma_f32_16x16x32_f16(a1f, bf, acc[1][nt], 0, 0, 0);
        }
        __syncthreads();
    }
#pragma unroll
    for (int rt = 0; rt < 2; ++rt) {
#pragma unroll
        for (int reg = 0; reg < 4; ++reg) {
            int m = bm0 + wave * 32 + rt * 16 + quad * 4 + reg;
            if (m < M) {
                float s = rowscale[m] * X8SCALE;
#pragma unroll
                for (int nt = 0; nt < 8; ++nt) {
                    int col = bn0 + nt * 16 + l15;
                    X8[(size_t)m * D_H + col] = enc_fp8(acc[rt][nt][reg] * s);
                }
            }
        }
    }
}

// ---- spmm layers 1,2: fp8 gather (lane-per-dword, MLP=16), BN+ReLU+residual; fp16 state ----
__global__ __launch_bounds__(256) void k_spmm12(const unsigned char* __restrict__ x8,
                                                const int* __restrict__ deg_in,
                                                const int* __restrict__ col_pad,
                                                const float* __restrict__ norm_dst,
                                                const float* __restrict__ bias,
                                                const float* __restrict__ gamma,
                                                const float* __restrict__ beta,
                                                const float* __restrict__ mean,
                                                const float* __restrict__ var,
                                                unsigned short* __restrict__ H, int n) {
    int wv = __builtin_amdgcn_readfirstlane(threadIdx.x >> 6);
    int r = blockIdx.x * 4 + wv;
    if (r >= n) return;
    int lane = threadIdx.x & 63;
    unsigned lb = (unsigned)lane << 2;      // byte offset of lane's dword in a 256B row
    int c = lane * 4;                       // dim base
    int d = deg_in[r]; if (d > PAD) d = PAD;
    int e0 = r * PAD, e1 = e0 + d;
    float ax = 0.f, ay = 0.f, az = 0.f, aw = 0.f;
    int e = e0;
    for (; e + 15 < e1; e += 16) {
        const intv4* cp = (const intv4*)(col_pad + e);
        intv4 i0 = __builtin_nontemporal_load(cp);
        intv4 i1 = __builtin_nontemporal_load(cp + 1);
        intv4 i2 = __builtin_nontemporal_load(cp + 2);
        intv4 i3 = __builtin_nontemporal_load(cp + 3);
        int s[16] = {i0.x, i0.y, i0.z, i0.w, i1.x, i1.y, i1.z, i1.w,
                     i2.x, i2.y, i2.z, i2.w, i3.x, i3.y, i3.z, i3.w};
        unsigned int w[16];
#pragma unroll
        for (int j = 0; j < 16; ++j)
            w[j] = *(const unsigned int*)(x8 + ((((unsigned)s[j]) << 8) | lb));
#pragma unroll
        for (int j = 0; j < 16; ++j) {
            float4 v = dec4_fp8(w[j]);
            ax += v.x; ay += v.y; az += v.z; aw += v.w;
        }
    }
    for (; e + 7 < e1; e += 8) {
        const intv4* cp = (const intv4*)(col_pad + e);
        intv4 i0 = __builtin_nontemporal_load(cp);
        intv4 i1 = __builtin_nontemporal_load(cp + 1);
        int s[8] = {i0.x, i0.y, i0.z, i0.w, i1.x, i1.y, i1.z, i1.w};
        unsigned int w[8];
#pragma unroll
        for (int j = 0; j < 8; ++j)
            w[j] = *(const unsigned int*)(x8 + ((((unsigned)s[j]) << 8) | lb));
#pragma unroll
        for (int j = 0; j < 8; ++j) {
            float4 v = dec4_fp8(w[j]);
            ax += v.x; ay += v.y; az += v.z; aw += v.w;
        }
    }
    for (; e < e1; ++e) {
        float4 v = dec4_fp8(*(const unsigned int*)(x8 + ((((unsigned)col_pad[e]) << 8) | lb)));
        ax += v.x; ay += v.y; az += v.z; aw += v.w;
    }
    float nd = norm_dst[r] * X8INV;
    float4 b4  = *(const float4*)(bias + c);
    float4 g4  = *(const float4*)(gamma + c);
    float4 be4 = *(const float4*)(beta + c);
    float4 m4  = *(const float4*)(mean + c);
    float4 v4  = *(const float4*)(var + c);
    float4 rv = load4h_nt(H + (size_t)r * D_H + c);   // residual read (line overwritten below)
    float4 o;
    o.x = fmaxf((ax * nd + b4.x - m4.x) * rsqrtf(v4.x + BN_EPS) * g4.x + be4.x, 0.f) + rv.x;
    o.y = fmaxf((ay * nd + b4.y - m4.y) * rsqrtf(v4.y + BN_EPS) * g4.y + be4.y, 0.f) + rv.y;
    o.z = fmaxf((az * nd + b4.z - m4.z) * rsqrtf(v4.z + BN_EPS) * g4.z + be4.z, 0.f) + rv.z;
    o.w = fmaxf((aw * nd + b4.w - m4.w) * rsqrtf(v4.w + BN_EPS) * g4.w + be4.w, 0.f) + rv.w;
    store4h(H + (size_t)r * D_H + c, o);
}

// ---------------- segmented mean-pool (graph_ids sorted), fp16 input ----------------
__global__ __launch_bounds__(256) void k_pool(const unsigned short* __restrict__ h,
                                              const int* __restrict__ gid,
                                              float* __restrict__ pooled,
                                              float* __restrict__ counts, int n) {
    int wave = threadIdx.x >> 6;
    int lane = threadIdx.x & 63;
    int base = blockIdx.x * 256 + wave * 64;
    if (base >= n) return;
    int c = lane * 4;
    int end = base + 64; if (end > n) end = n;
    float ax = 0.f, ay = 0.f, az = 0.f, aw = 0.f;
    int cnt = 0, cur = -1;
    for (int i = base; i < end; ++i) {
        int g = gid[i];
        if (g != cur) {
            if (cnt > 0) {
                atomicAdd(&pooled[cur * D_H + c + 0], ax);
                atomicAdd(&pooled[cur * D_H + c + 1], ay);
                atomicAdd(&pooled[cur * D_H + c + 2], az);
                atomicAdd(&pooled[cur * D_H + c + 3], aw);
                if (lane == 0) atomicAdd(&counts[cur], (float)cnt);
            }
            cur = g; cnt = 0; ax = ay = az = aw = 0.f;
        }
        float4 v = load4h(h + (size_t)i * D_H + c);
        ax += v.x; ay += v.y; az += v.z; aw += v.w;
        cnt++;
    }
    if (cnt > 0) {
        atomicAdd(&pooled[cur * D_H + c + 0], ax);
        atomicAdd(&pooled[cur * D_H + c + 1], ay);
        atomicAdd(&pooled[cur * D_H + c + 2], az);
        atomicAdd(&pooled[cur * D_H + c + 3], aw);
        if (lane == 0) atomicAdd(&counts[cur], (float)cnt);
    }
}

// -------- head: out[g] = (pooled[g]/count[g]) @ Wp + bp  (fp32 in/out) --------
__global__ __launch_bounds__(64) void k_head(const float* __restrict__ pooled,
                                             const float* __restrict__ counts,
                                             const float* __restrict__ Wp,
                                             const float* __restrict__ bp,
                                             float* __restrict__ out) {
    int g = blockIdx.x;
    int t = threadIdx.x;
    __shared__ float p[D_H];
    float inv = 1.0f / fmaxf(counts[g], 1.0f);
    for (int k = t; k < D_H; k += 64) p[k] = pooled[g * D_H + k] * inv;
    __syncthreads();
    float acc = bp[t];
#pragma unroll 8
    for (int k = 0; k < D_H; ++k) acc = fmaf(p[k], Wp[k * D_OUT + t], acc);
    out[g * D_OUT + t] = acc;
}

extern "C" void kernel_launch(void* const* d_in, const int* in_sizes, int n_in,
                              void* d_out, int out_size, void* d_ws, size_t ws_size,
                              hipStream_t stream) {
    (void)in_sizes; (void)n_in; (void)out_size; (void)ws_size;
    const float* h        = (const float*)d_in[0];
    const float* W0       = (const float*)d_in[1];
    const float* b0       = (const float*)d_in[2];
    const float* Wl       = (const float*)d_in[3];
    const float* bl       = (const float*)d_in[4];
    const float* bn_gamma = (const float*)d_in[5];
    const float* bn_beta  = (const float*)d_in[6];
    const float* bn_mean  = (const float*)d_in[7];
    const float* bn_var   = (const float*)d_in[8];
    const float* Wp       = (const float*)d_in[9];
    const float* bp       = (const float*)d_in[10];
    const int*   src      = (const int*)d_in[11];
    const int*   dst      = (const int*)d_in[12];
    const int*   gid      = (const int*)d_in[13];
    float* out = (float*)d_out;

    char* ws = (char*)d_ws;
    size_t off = 0;
    auto alloc = [&](size_t bytes) -> void* {
        void* p = ws + off;
        off += (bytes + 255) & ~(size_t)255;
        return p;
    };
    unsigned int*   bufXh8 = (unsigned int*)alloc((size_t)NN * D_IN);       // fp8 h*ns (12.8 MB)
    unsigned char*  bufX8  = (unsigned char*)alloc((size_t)NN * D_H);       // fp8 messages (25.6 MB)
    unsigned short* bufH   = (unsigned short*)alloc((size_t)NN * D_H * 2);  // fp16 state (51.2 MB)
    unsigned short* bufP   = (unsigned short*)alloc((size_t)NN * D_IN * 2); // agg fp16 (25.6 MB)
    int*   col_pad  = (int*)alloc(((size_t)NN * PAD + 64) * 4);             // 38.4 MB
    float* norm_src = (float*)alloc((size_t)NN * 4);
    float* norm_dst = (float*)alloc((size_t)NN * 4);
    int*   degs     = (int*)alloc(((size_t)NN + 2 * NBUCK) * 4);
    int*   deg_in   = degs;
    int*   cursor   = degs + NN;                                            // NBUCK ints
    int*   scursor  = degs + NN + NBUCK;                                    // NBUCK ints
    unsigned short* wsplit = (unsigned short*)alloc(163840 * 2);            // fp16 W transposed
    float* pooled   = (float*)alloc((size_t)(GG * D_H + GG) * 4);
    float* counts   = pooled + GG * D_H;

    // bucketed edge buffer aliases bufX8 (dead until layer-1 k_gemm_x): 16.0 MB <= 25.6 MB
    int* ebuf = (int*)bufX8;
    // src-bucket byte buffer aliases bufH (dead until k_gemm_bn writes H): 4.0 MB <= 51.2 MB
    unsigned char* sbuf = (unsigned char*)bufH;

    unsigned short* w0T = wsplit;            // [256][128]
    unsigned short* w1T = wsplit + 32768;    // [256][256]
    unsigned short* w2T = wsplit + 98304;    // [256][256]

    hipMemsetAsync(cursor, 0, (size_t)2 * NBUCK * 4, stream);
    hipMemsetAsync(pooled, 0, (size_t)(GG * D_H + GG) * 4, stream);

    const int NB = (NN + 255) / 256;
    const int SB = (NN + 3) / 4;
    const int SB0 = (NN + 7) / 8;

    k_splitw<<<640, 256, 0, stream>>>(W0, Wl, wsplit);
    k_bucket<<<(EE + 1024 * EPT - 1) / (1024 * EPT), 1024, 0, stream>>>(
        src, dst, cursor, scursor, ebuf, sbuf, EE);
    k_fill<<<NBUCK, 512, 0, stream>>>(cursor, scursor, ebuf, sbuf, h, col_pad, deg_in,
                                      norm_src, norm_dst, bufXh8);

    // layer 0: aggregate-first (128-dim fp8 gather, 2 rows/wave)
    k_spmm0<<<SB0, 256, 0, stream>>>((const unsigned char*)bufXh8, deg_in, col_pad,
                                     norm_dst, bufP, NN);
    k_gemm_bn<<<GEMM_NWG, 256, 0, stream>>>(bufP, w0T, b0,
                                            bn_gamma, bn_beta, bn_mean, bn_var,
                                            bufH, NN, D_IN);
    // layer 1 (fp8 messages)
    k_gemm_x<<<GEMM_NWG, 256, 0, stream>>>(bufH, w1T, norm_src, bufX8, NN, D_H);
    k_spmm12<<<SB, 256, 0, stream>>>(bufX8, deg_in, col_pad, norm_dst, bl,
                                     bn_gamma + D_H, bn_beta + D_H,
                                     bn_mean + D_H, bn_var + D_H, bufH, NN);
    // layer 2
    k_gemm_x<<<GEMM_NWG, 256, 0, stream>>>(bufH, w2T, norm_src, bufX8, NN, D_H);
    k_spmm12<<<SB, 256, 0, stream>>>(bufX8, deg_in, col_pad, norm_dst, bl + D_H,
                                     bn_gamma + 2 * D_H, bn_beta + 2 * D_H,
                                     bn_mean + 2 * D_H, bn_var + 2 * D_H, bufH, NN);

    k_pool<<<NB, 256, 0, stream>>>(bufH, gid, pooled, counts, NN);
    k_head<<<GG, 64, 0, stream>>>(pooled, counts, Wp, bp, out);
}